// Round 4
// baseline (137.542 us; speedup 1.0000x reference)
//
#include <hip/hip_runtime.h>

#define N_DIM 4
#define C_DIM 256
#define T_DIM 5
#define HW    784
#define L_TOK 3920   // T*H*W
#define CI    128
#define CA    128

// ws layout (floats):
//   [0,     5120)   Xs     [N][T][C]
//   [8192,  40960)  alignT [CA][C]   (= align_W^T)
//   [40960, 73728)  phiT   [C][CI]   (= phi_W^T)
//   [73728, 106496) gT     [C][CI]   (= g_W^T)
//   [106496,139264) WzT    [CI][C]   (= Wz_W^T)
#define WS_XS   0
#define WS_TR   8192          // start of the 4 transposed matrices (contiguous)

// ---------------- kernel A: Xs + weight transposes ----------------
// blocks [0,5120): Xs[n,t,c] = sum_{h,w} x[n,c,t,h,w]
// blocks [5120,5248): transpose align_W, phi_W, g_W, Wz_W into ws
__global__ __launch_bounds__(256) void kA(const float* __restrict__ x,
                                          const float* __restrict__ align_W,
                                          const float* __restrict__ phi_W,
                                          const float* __restrict__ g_W,
                                          const float* __restrict__ Wz_W,
                                          float* __restrict__ ws) {
    int bid = blockIdx.x;
    int tid = threadIdx.x;
    if (bid < N_DIM * C_DIM * T_DIM) {
        int n   = bid / (C_DIM * T_DIM);
        int rem = bid % (C_DIM * T_DIM);
        int c   = rem / T_DIM;
        int t   = rem % T_DIM;
        const float4* base = (const float4*)(x + ((size_t)(n * C_DIM + c) * T_DIM + t) * HW);
        float p = 0.f;
        if (tid < HW / 4) {
            float4 v = base[tid];
            p = (v.x + v.y) + (v.z + v.w);
        }
        for (int off = 32; off > 0; off >>= 1) p += __shfl_down(p, off, 64);
        __shared__ float wsum[4];
        if ((tid & 63) == 0) wsum[tid >> 6] = p;
        __syncthreads();
        if (tid == 0)
            ws[WS_XS + (n * T_DIM + t) * C_DIM + c] = wsum[0] + wsum[1] + wsum[2] + wsum[3];
    } else {
        // 128 transpose blocks, 1024 dst elements each; dst-linear (coalesced writes)
        int tb = bid - N_DIM * C_DIM * T_DIM;        // 0..127; 32 blocks per matrix
        #pragma unroll
        for (int k = 0; k < 4; ++k) {
            int D = tb * 1024 + k * 256 + tid;       // global dst index 0..131071
            int m = D >> 15;                          // which matrix
            int r = D & 32767;
            float v;
            if (m == 0)      { int a = r >> 8, c = r & 255; v = align_W[c * CA + a]; }
            else if (m == 1) { int c = r >> 7, o = r & 127; v = phi_W[o * C_DIM + c]; }
            else if (m == 2) { int c = r >> 7, o = r & 127; v = g_W[o * C_DIM + c]; }
            else             { int o = r >> 8, c = r & 255; v = Wz_W[c * CI + o]; }
            ws[WS_TR + D] = v;
        }
    }
}

// ---------------- kernel B: per-n chain + F + epilogue + residual + LN ----------------
// grid (62 tiles, 4 n) x 1024 threads = 16 groups x 64 tokens
__global__ __launch_bounds__(1024) void kB(
    const float* __restrict__ x,        const float* __restrict__ ws,
    const float* __restrict__ audio,    const float* __restrict__ align_b,
    const float* __restrict__ g_b,      const float* __restrict__ theta_W,
    const float* __restrict__ theta_b,  const float* __restrict__ phi_b,
    const float* __restrict__ Wz_b,     const float* __restrict__ bn_gamma,
    const float* __restrict__ bn_beta,  const float* __restrict__ bn_mean,
    const float* __restrict__ bn_var,   const float* __restrict__ ln_gamma,
    const float* __restrict__ ln_beta,  float* __restrict__ out,
    float* __restrict__ out_audio) {
    __shared__ float audio_s[T_DIM * CA];        // 640
    __shared__ float xs_s[T_DIM * C_DIM];        // 1280
    __shared__ float at_s[T_DIM * C_DIM];        // 1280
    __shared__ float phi_s[T_DIM * CI];          // 640
    __shared__ float g2_s[T_DIM * CI];           // 640
    __shared__ float TPs[T_DIM * C_DIM];         // 1280
    __shared__ float GWs[T_DIM * C_DIM];         // 1280
    __shared__ float tb_s[T_DIM];
    __shared__ float B_s[C_DIM], inv_s[C_DIM], lng_s[C_DIM], lnb_s[C_DIM];
    __shared__ float Fp[T_DIM * 1024];           // 5120
    __shared__ float Sp[2 * 1024];               // 2048

    int n    = blockIdx.y;
    int tile = blockIdx.x;
    int tid  = threadIdx.x;
    int g    = tid >> 6;        // channel group 0..15 (wave id)
    int li   = tid & 63;        // token within tile
    int l    = tile * 64 + li;
    bool act = (l < L_TOK);

    const float* alignT = ws + WS_TR;             // [CA][C]
    const float* phiT   = ws + WS_TR + 32768;     // [C][CI]
    const float* gT     = ws + WS_TR + 65536;     // [C][CI]
    const float* WzT    = ws + WS_TR + 98304;     // [CI][C]

    // ---- stage ----
    if (tid < T_DIM * CA) audio_s[tid] = audio[n * T_DIM * CA + tid];
    for (int i = tid; i < T_DIM * C_DIM; i += 1024) xs_s[i] = ws[WS_XS + n * T_DIM * C_DIM + i];
    if (tid < C_DIM) {
        int c = tid;
        float inv = bn_gamma[c] * rsqrtf(bn_var[c] + 1e-5f);
        inv_s[c] = inv * (1.0f / (float)L_TOK);
        B_s[c]   = (Wz_b[c] - bn_mean[c]) * inv + bn_beta[c];
        lng_s[c] = ln_gamma[c];
        lnb_s[c] = ln_beta[c];
    }
    __syncthreads();

    // ---- B1: at[t][c] = audio[t,:] . align_W[c,:] + align_b[c]  (coalesced via alignT) ----
    for (int i = tid; i < T_DIM * C_DIM; i += 1024) {
        int t = i >> 8, c = i & 255;
        float a0 = 0, a1 = 0, a2 = 0, a3 = 0;
        const float* as = audio_s + t * CA;
        #pragma unroll 8
        for (int a = 0; a < CA; a += 4) {
            a0 = fmaf(alignT[(a + 0) * C_DIM + c], as[a + 0], a0);
            a1 = fmaf(alignT[(a + 1) * C_DIM + c], as[a + 1], a1);
            a2 = fmaf(alignT[(a + 2) * C_DIM + c], as[a + 2], a2);
            a3 = fmaf(alignT[(a + 3) * C_DIM + c], as[a + 3], a3);
        }
        float v = align_b[c] + (a0 + a1) + (a2 + a3);
        at_s[i] = v;
        if (tile == 0) out_audio[n * T_DIM * C_DIM + i] = v;   // 2nd tuple output
    }
    __syncthreads();

    // ---- B2: phi[t][o], G[t][o]  (coalesced via phiT/gT; at/xs broadcast from LDS) ----
    if (tid < T_DIM * CI) {
        int t = tid >> 7, o = tid & 127;
        const float* ats = at_s + t * C_DIM;
        const float* xss = xs_s + t * C_DIM;
        float p0 = 0, p1 = 0, q0 = 0, q1 = 0;
        #pragma unroll 8
        for (int c = 0; c < C_DIM; c += 2) {
            p0 = fmaf(phiT[(c + 0) * CI + o], ats[c + 0], p0);
            p1 = fmaf(phiT[(c + 1) * CI + o], ats[c + 1], p1);
            q0 = fmaf(gT[(c + 0) * CI + o],  xss[c + 0], q0);
            q1 = fmaf(gT[(c + 1) * CI + o],  xss[c + 1], q1);
        }
        phi_s[tid] = phi_b[o] + p0 + p1;
        g2_s[tid]  = (float)HW * g_b[o] + q0 + q1;
    }
    __syncthreads();

    // ---- B3: TP[t][c], GW[t][c], tb[t] ----
    for (int i = tid; i < T_DIM * C_DIM; i += 1024) {
        int t = i >> 8, c = i & 255;
        const float* ps = phi_s + t * CI;
        const float* gs = g2_s + t * CI;
        float a0 = 0, a1 = 0, b0 = 0, b1 = 0;
        #pragma unroll 8
        for (int o = 0; o < CI; o += 2) {
            a0 = fmaf(theta_W[(o + 0) * C_DIM + c], ps[o + 0], a0);
            a1 = fmaf(theta_W[(o + 1) * C_DIM + c], ps[o + 1], a1);
            b0 = fmaf(WzT[(o + 0) * C_DIM + c],     gs[o + 0], b0);
            b1 = fmaf(WzT[(o + 1) * C_DIM + c],     gs[o + 1], b1);
        }
        TPs[i] = a0 + a1;
        GWs[i] = (b0 + b1) * inv_s[c];
    }
    if (tid < T_DIM * 64) {                      // tb[t]: one wave per t
        int t = tid >> 6, lane = tid & 63;
        float p = theta_b[lane] * phi_s[t * CI + lane] +
                  theta_b[lane + 64] * phi_s[t * CI + lane + 64];
        for (int off = 32; off > 0; off >>= 1) p += __shfl_down(p, off, 64);
        if (lane == 0) tb_s[t] = p;
    }
    __syncthreads();

    // ---- B4: load 16 channels of token l; F[t] partials ----
    float xz[16];
    const float* xb = x + ((size_t)(n * C_DIM + g * 16)) * L_TOK + l;
    #pragma unroll
    for (int j = 0; j < 16; ++j) xz[j] = act ? xb[(size_t)j * L_TOK] : 0.f;

    float F0 = 0, F1 = 0, F2 = 0, F3 = 0, F4 = 0;
    #pragma unroll
    for (int j = 0; j < 16; ++j) {
        const float* tp = TPs + g * 16 + j;
        F0 = fmaf(xz[j], tp[0],    F0);
        F1 = fmaf(xz[j], tp[256],  F1);
        F2 = fmaf(xz[j], tp[512],  F2);
        F3 = fmaf(xz[j], tp[768],  F3);
        F4 = fmaf(xz[j], tp[1024], F4);
    }
    Fp[0 * 1024 + tid] = F0; Fp[1 * 1024 + tid] = F1; Fp[2 * 1024 + tid] = F2;
    Fp[3 * 1024 + tid] = F3; Fp[4 * 1024 + tid] = F4;
    __syncthreads();

    // ---- B5: full F per token, z over own channels, stats ----
    float Ft[T_DIM];
    #pragma unroll
    for (int t = 0; t < T_DIM; ++t) {
        float a = tb_s[t];
        #pragma unroll
        for (int w = 0; w < 16; ++w) a += Fp[t * 1024 + w * 64 + li];
        Ft[t] = a;
    }
    float s1 = 0.f, s2 = 0.f;
    #pragma unroll
    for (int j = 0; j < 16; ++j) {
        int c = g * 16 + j;
        float zc = B_s[c] + xz[j];
        zc = fmaf(Ft[0], GWs[c],        zc);
        zc = fmaf(Ft[1], GWs[256 + c],  zc);
        zc = fmaf(Ft[2], GWs[512 + c],  zc);
        zc = fmaf(Ft[3], GWs[768 + c],  zc);
        zc = fmaf(Ft[4], GWs[1024 + c], zc);
        xz[j] = zc;
        s1 += zc;
        s2 = fmaf(zc, zc, s2);
    }
    Sp[tid]        = s1;
    Sp[1024 + tid] = s2;
    __syncthreads();

    // ---- B6: LayerNorm over channels, write out ----
    float t1 = 0.f, t2 = 0.f;
    #pragma unroll
    for (int w = 0; w < 16; ++w) {
        t1 += Sp[w * 64 + li];
        t2 += Sp[1024 + w * 64 + li];
    }
    float mu   = t1 * (1.0f / C_DIM);
    float var  = t2 * (1.0f / C_DIM) - mu * mu;
    float rstd = rsqrtf(var + 1e-5f);
    if (act) {
        float* ob = out + ((size_t)(n * C_DIM + g * 16)) * L_TOK + l;
        #pragma unroll
        for (int j = 0; j < 16; ++j) {
            int c = g * 16 + j;
            ob[(size_t)j * L_TOK] = fmaf((xz[j] - mu) * rstd, lng_s[c], lnb_s[c]);
        }
    }
}

extern "C" void kernel_launch(void* const* d_in, const int* in_sizes, int n_in,
                              void* d_out, int out_size, void* d_ws, size_t ws_size,
                              hipStream_t stream) {
    const float* x        = (const float*)d_in[0];
    const float* audio    = (const float*)d_in[1];
    const float* align_W  = (const float*)d_in[2];
    const float* align_b  = (const float*)d_in[3];
    const float* g_W      = (const float*)d_in[4];
    const float* g_b      = (const float*)d_in[5];
    const float* theta_W  = (const float*)d_in[6];
    const float* theta_b  = (const float*)d_in[7];
    const float* phi_W    = (const float*)d_in[8];
    const float* phi_b    = (const float*)d_in[9];
    const float* Wz_W     = (const float*)d_in[10];
    const float* Wz_b     = (const float*)d_in[11];
    const float* bn_gamma = (const float*)d_in[12];
    const float* bn_beta  = (const float*)d_in[13];
    const float* bn_mean  = (const float*)d_in[14];
    const float* bn_var   = (const float*)d_in[15];
    const float* ln_gamma = (const float*)d_in[16];
    const float* ln_beta  = (const float*)d_in[17];

    float* out       = (float*)d_out;
    float* out_audio = out + (size_t)N_DIM * C_DIM * L_TOK;   // 4,014,080
    float* ws        = (float*)d_ws;

    kA<<<N_DIM * C_DIM * T_DIM + 128, 256, 0, stream>>>(x, align_W, phi_W, g_W, Wz_W, ws);
    dim3 gridB((L_TOK + 63) / 64, N_DIM);
    kB<<<gridB, 1024, 0, stream>>>(
        x, ws, audio, align_b, g_b, theta_W, theta_b, phi_b,
        Wz_b, bn_gamma, bn_beta, bn_mean, bn_var, ln_gamma, ln_beta,
        out, out_audio);
}